// Round 2
// 1894.282 us; speedup vs baseline: 1.4751x; 1.4751x over previous
//
#include <hip/hip_runtime.h>
#include <hip/hip_fp16.h>

#define T_DIM 1024
#define B_DIM 64
#define F_DIM 512
#define H_DIM 512
#define G4    2048
#define HSZ   (B_DIM*H_DIM)   // 32768

typedef _Float16 h16;
typedef unsigned long long u64;
typedef _Float16 v8h __attribute__((ext_vector_type(8)));
typedef _Float16 v4h __attribute__((ext_vector_type(4)));
typedef _Float16 v2h __attribute__((ext_vector_type(2)));
typedef float    v4f __attribute__((ext_vector_type(4)));
typedef unsigned v4u __attribute__((ext_vector_type(4)));
typedef unsigned v2u __attribute__((ext_vector_type(2)));

// scan decomposition: 8 row-groups x 8 rows, 16 WGs per group (grid 128).
// Teams formed by XCD census so each group's 16 WGs share one XCD ->
// h exchange via that XCD's L2 (plain store + nt load) instead of MALL.
// nt (not sc0!): sc0 = workgroup scope = L1-served = stale-poll hang.
// nt never allocates in L1; if nt bypasses L2 on this part, the bounded
// trial fails (plain store stays dirty in L2) and we degrade gracefully.
#define NGRP   8
#define GROWS  8
#define GWORDS 2048            // (8 rows * 512 units) / 2 fp16 per word
#define NWG    128
#define DESC_OFF  ((size_t)2*NGRP*GWORDS)     // census descriptors
#define TRIAL_OFF (DESC_OFF + NWG)            // visibility trial words
#define VOTE_OFF  (TRIAL_OFF + NWG)           // unanimity votes
#define ABORT_OFF (VOTE_OFF + NWG)            // per-group abort words

// workspace layout (bytes):
//   [0, 256MB)            xp: h16 [T][256 wg][2 tile][64 lane][4 reg]
//   [+0, +~260KB)         hbuf: u64 [2 phase][8 group][2048] + desc/trial/vote/abort
//   [.., +64MB)           X16: fp16 copy of X [B][T][F]
//   [.., +2MB)            Wxp: fp16 permuted Wx [2048 pc][512 k]
#define XP_HALVES ((size_t)T_DIM * 256 * 2 * 64 * 4)
#define XP_BYTES  (XP_HALVES * 2)
#define HB_WORDS  (ABORT_OFF + NGRP)
#define HB_BYTES  (HB_WORDS * 8)
#define X16_BYTES ((size_t)B_DIM * T_DIM * F_DIM * 2)   // 64 MB
#define WXP_BYTES ((size_t)G4 * F_DIM * 2)              // 2 MB

// ---------------------------------------------------------------------------
// Phase 0a: X fp32 -> fp16, straight copy (bandwidth-bound).
// ---------------------------------------------------------------------------
__global__ __launch_bounds__(256) void conv_x_kernel(
    const float* __restrict__ X, h16* __restrict__ X16)
{
  const size_t total4 = (size_t)B_DIM * T_DIM * F_DIM / 4;   // 8388608
  for (size_t i = blockIdx.x * 256 + threadIdx.x; i < total4;
       i += (size_t)gridDim.x * 256) {
    float4 v = ((const float4*)X)[i];
    v4h w = { (h16)v.x, (h16)v.y, (h16)v.z, (h16)v.w };
    ((v4h*)X16)[i] = w;
  }
}

// ---------------------------------------------------------------------------
// Phase 0b: Wx fp32 -> Wxp[pc][k] fp16, pre-permuted into staging order.
// ---------------------------------------------------------------------------
__global__ __launch_bounds__(256) void conv_w_kernel(
    const float* __restrict__ Wx, h16* __restrict__ Wxp)
{
  const int gid = blockIdx.x * 256 + threadIdx.x;   // 512 blocks -> 131072
  const int pcg = gid >> 6;                         // 0..2047
  const int k8  = gid & 63;                         // 0..63 (8 k's each)
  const int ub  = pcg >> 5, Tt = (pcg >> 4) & 1, nn = pcg & 15;
  const int gcol = (Tt*2 + (nn >> 3))*512 + ub*8 + (nn & 7);
  v8h w;
  #pragma unroll
  for (int j = 0; j < 8; ++j)
    w[j] = (h16)Wx[(size_t)(k8*8 + j)*G4 + gcol];
  *(v8h*)(Wxp + (size_t)pcg*512 + k8*8) = w;
}

// ---------------------------------------------------------------------------
// Phase 1: x_proj = X16 @ Wxp + b -> fp16 MFMA C/D fragment layout (unchanged).
// ---------------------------------------------------------------------------
__global__ __launch_bounds__(256) void xproj_kernel(
    const h16* __restrict__ X16, const h16* __restrict__ Wxp,
    const float* __restrict__ bias, h16* __restrict__ xp)
{
  __shared__ __align__(16) h16 As[128*72];
  __shared__ __align__(16) h16 Bs[128*72];
  const int wgid = blockIdx.x;               // 8192 blocks
  const int wgn  = wgid & 15;
  const int bg   = (wgid >> 4) & 3;
  const int t0   = (wgid >> 6) * 8;
  const int tid  = threadIdx.x;
  const int lane = tid & 63;
  const int wv   = tid >> 6;
  const int mh   = wv & 1, nh = wv >> 1;
  const int n    = lane & 15, quad = lane >> 4;

  v4f acc[4][4];
  #pragma unroll
  for (int mi = 0; mi < 4; ++mi)
    #pragma unroll
    for (int ni = 0; ni < 4; ++ni) acc[mi][ni] = {0.f, 0.f, 0.f, 0.f};

  const int m  = tid >> 1;
  const int kh = tid & 1;
  const int abl = m & 15, atl = m >> 4;
  const h16* asrc0 = X16 + ((size_t)(bg*16 + abl)*T_DIM + (t0 + atl))*F_DIM
                         + kh*32;
  const h16* bsrc0 = Wxp + (size_t)(wgn*128 + m)*512 + kh*32;
  h16* adst = As + m*72 + kh*32;
  h16* bdst = Bs + m*72 + kh*32;

  for (int kc = 0; kc < 8; ++kc) {
    __syncthreads();
    {
      const h16* asrc = asrc0 + kc*64;
      const h16* bsrc = bsrc0 + kc*64;
      #pragma unroll
      for (int j = 0; j < 32; j += 8) {
        *(v8h*)(adst + j) = *(const v8h*)(asrc + j);
        *(v8h*)(bdst + j) = *(const v8h*)(bsrc + j);
      }
    }
    __syncthreads();
    #pragma unroll
    for (int kk = 0; kk < 2; ++kk) {
      v8h aF[4], bF[4];
      #pragma unroll
      for (int mi = 0; mi < 4; ++mi)
        aF[mi] = *(const v8h*)(As + ((mh*4 + mi)*16 + n)*72 + kk*32 + quad*8);
      #pragma unroll
      for (int ni = 0; ni < 4; ++ni)
        bF[ni] = *(const v8h*)(Bs + ((nh*4 + ni)*16 + n)*72 + kk*32 + quad*8);
      #pragma unroll
      for (int mi = 0; mi < 4; ++mi)
        #pragma unroll
        for (int ni = 0; ni < 4; ++ni)
          acc[mi][ni] = __builtin_amdgcn_mfma_f32_16x16x32_f16(
              aF[mi], bF[ni], acc[mi][ni], 0, 0, 0);
    }
  }
  #pragma unroll
  for (int ni = 0; ni < 4; ++ni) {
    int pc0  = wgn*128 + (nh*4 + ni)*16;
    int ub   = pc0 >> 5, Tt = (pc0 >> 4) & 1;
    int gcol = (Tt*2 + (n >> 3))*512 + ub*8 + (n & 7);
    float bv = bias[gcol];
    int wg2  = bg*64 + ub;
    #pragma unroll
    for (int mi = 0; mi < 4; ++mi) {
      int t = t0 + mh*4 + mi;
      size_t off = ((((size_t)t*256 + wg2)*2 + Tt)*256) + lane*4;
      v4h o = { (h16)(acc[mi][ni][0] + bv), (h16)(acc[mi][ni][1] + bv),
                (h16)(acc[mi][ni][2] + bv), (h16)(acc[mi][ni][3] + bv) };
      *(v4h*)(xp + off) = o;
    }
  }
}

// ---------------------------------------------------------------------------
// Phase 2: persistent scan with XCD-local exchange (nt poll + watchdog).
// ---------------------------------------------------------------------------
__device__ __forceinline__ float fsig(float x) {
  return __builtin_amdgcn_rcpf(1.f + __expf(-x));
}
__device__ __forceinline__ float ftanh(float x) {
  return 1.f - 2.f * __builtin_amdgcn_rcpf(__expf(2.f*x) + 1.f);
}

// nt load: no L1 allocation; served by XCD L2 when the line is there.
__device__ __forceinline__ u64 load_nt_u64(const u64* p) {
  v2u r;
  asm volatile("global_load_dwordx2 %0, %1, off nt\n\ts_waitcnt vmcnt(0)"
               : "=v"(r) : "v"(p) : "memory");
  return ((u64)r.y << 32) | (u64)r.x;
}

__global__ __launch_bounds__(256, 1) void scan_kernel(
    const float* __restrict__ Wh, const h16* __restrict__ xp,
    u64* __restrict__ hbuf, float* __restrict__ out)
{
  const int bx   = blockIdx.x;          // 0..127
  const int tid  = threadIdx.x;         // 0..255
  const int wv   = tid >> 6;
  const int lane = tid & 63;
  const int n    = lane & 15, quad = lane >> 4;

  __shared__ __align__(16) unsigned hlds[2][2052];  // 2048 payloads + zero pad
  __shared__ float gbuf[4][16*33];                  // per-wave gate exchange
  __shared__ unsigned char xcds[NWG];
  __shared__ unsigned char pos2bx[NWG];
  __shared__ int sflag[2];

  // ---- census: read physical XCD, publish, gather (always completes:
  // every WG writes its descriptor before any wait; 128 WGs <= 256 CUs). ----
  unsigned xcd;
  asm volatile("s_getreg_b32 %0, hwreg(20, 0, 32)" : "=s"(xcd)); // XCC_ID
  xcd &= 7u;
  u64* const desc = hbuf + DESC_OFF;
  if (tid == 0)
    __hip_atomic_store(desc + bx, ((u64)0xABu << 56) | (u64)xcd,
                       __ATOMIC_RELAXED, __HIP_MEMORY_SCOPE_AGENT);
  if (tid < NWG) {
    u64 d = __hip_atomic_load(desc + tid, __ATOMIC_RELAXED,
                              __HIP_MEMORY_SCOPE_AGENT);
    while ((unsigned)(d >> 56) != 0xABu) {
      __builtin_amdgcn_s_sleep(1);
      d = __hip_atomic_load(desc + tid, __ATOMIC_RELAXED,
                            __HIP_MEMORY_SCOPE_AGENT);
    }
    xcds[tid] = (unsigned char)(d & 7u);
  }
  if (tid < 4) { hlds[0][2048 + tid] = 0; hlds[1][2048 + tid] = 0; }
  __syncthreads();

  // deterministic team assignment: sort WGs by (xcd, bx); 16 consecutive
  // positions = one group. Fast iff the whole group sits in one xcd bucket
  // (spanning groups see fast=false unanimously by construction).
  int start = 0, cnt = 0, rank = 0;
  for (int i = 0; i < NWG; ++i) {
    const int x = xcds[i];
    start += (x < (int)xcd) ? 1 : 0;
    cnt   += (x == (int)xcd) ? 1 : 0;
    rank  += (x == (int)xcd && i < bx) ? 1 : 0;
  }
  const int pos = start + rank;
  const int g = pos >> 4, w = pos & 15;     // group 0..7, slot 0..15
  bool fast = (g*16 >= start) && (g*16 + 16 <= start + cnt);

  // ---- trial handshake: plain-store -> nt-load visibility on this exact
  // placement; bounded wait, then agent-scope unanimous vote. Tests the same
  // instruction classes as the steady loop. Failure => slow path, no hang. ----
  if (fast) {
    if (tid < NWG) {
      const int xi = xcds[tid];
      int st = 0, rk = 0;
      for (int i = 0; i < NWG; ++i) {
        const int x = xcds[i];
        st += (x < xi) ? 1 : 0;
        rk += (x == xi && i < tid) ? 1 : 0;
      }
      pos2bx[st + rk] = (unsigned char)tid;
    }
    __syncthreads();
    u64* const trial = hbuf + TRIAL_OFF;
    u64* const vote  = hbuf + VOTE_OFF;
    if (tid == 0)
      __hip_atomic_store(trial + bx, ((u64)0xCDu << 56) | (u64)bx,
                         __ATOMIC_RELAXED, __HIP_MEMORY_SCOPE_WORKGROUP);
    int seen = 1;
    if (tid < 16) {
      const int tb = pos2bx[g*16 + tid];
      const u64 want = ((u64)0xCDu << 56) | (u64)tb;
      seen = 0;
      for (int it = 0; it < 1024; ++it) {
        if (load_nt_u64(trial + tb) == want) { seen = 1; break; }
        __builtin_amdgcn_s_sleep(1);
      }
    }
    if (tid < 64) {
      const int okw = __all(seen);
      if (tid == 0) sflag[0] = okw;
    }
    __syncthreads();
    if (tid == 0)
      __hip_atomic_store(vote + bx, ((u64)0xEFu << 56) | (u64)(sflag[0] & 1),
                         __ATOMIC_RELAXED, __HIP_MEMORY_SCOPE_AGENT);
    int vok = 1;
    if (tid < 16) {
      const int tb = pos2bx[g*16 + tid];
      u64 d = __hip_atomic_load(vote + tb, __ATOMIC_RELAXED,
                                __HIP_MEMORY_SCOPE_AGENT);
      while ((unsigned)(d >> 56) != 0xEFu) {
        __builtin_amdgcn_s_sleep(1);
        d = __hip_atomic_load(vote + tb, __ATOMIC_RELAXED,
                              __HIP_MEMORY_SCOPE_AGENT);
      }
      vok = (int)(d & 1);
    }
    if (tid < 64) {
      const int allv = __all(vok);
      if (tid == 0) sflag[1] = allv;
    }
    __syncthreads();
    fast = (sflag[1] != 0);
  }

  const int ub  = w*4 + wv;           // unit-block 0..63 (8 units)
  const int u0  = ub*8;
  const int g01 = n >> 3;
  const int uc  = u0 + (n & 7);

  // persistent B fragments: tile0 = gates {i,f}, tile1 = {g,o}
  v8h bF0[16], bF1[16];
  #pragma unroll
  for (int kk = 0; kk < 16; ++kk) {
    const int kb = kk*32 + quad*8;
    v8h f0, f1;
    #pragma unroll
    for (int j = 0; j < 8; ++j) {
      f0[j] = (h16)Wh[(size_t)(kb + j)*G4 + (g01*512 + uc)];
      f1[j] = (h16)Wh[(size_t)(kb + j)*G4 + ((2 + g01)*512 + uc)];
    }
    bF0[kk] = f0; bF1[kk] = f1;
  }

  float c0 = 0.f, c1 = 0.f, hf0 = 0.f, hf1 = 0.f;

  const bool act = (n < GROWS);              // h-owner lane (row n, 2 units)
  const int  pW  = ub*32 + n*4 + quad;       // producer word index
  u64* const gbase0 = hbuf + (size_t)g * GWORDS;
  u64* const gbase1 = hbuf + (size_t)(NGRP + g) * GWORDS;
  u64* const abw    = hbuf + ABORT_OFF + g;
  u64* const gb0p   = gbase0 + pW;           // deref gated by lw0 != 0
  u64* const gb1p   = gbase1 + pW;
  u64 lw0 = 0, lw1 = 0;                      // last plain-stored words (flush)

  // xp fragment remap: group g rows = old 16-row group (g>>1), quads (g&1)*2+{0,1}
  const int bgrp  = g >> 1;
  const int qq    = (g & 1)*2 + (quad & 1);
  const int lanep = n + 16*qq;
  size_t xoff = ((size_t)(bgrp*64 + ub)*2)*256 + lanep*4;
  v4h x0 = *(const v4h*)(xp + xoff);
  v4h x1 = *(const v4h*)(xp + xoff + 256);

  // A-fragment base in hlds (linear word layout); pad rows read the zero pad
  const int hbase = act ? (quad*32 + n*4) : 2048;
  const int hoff  = act ? 128 : 0;

  for (int t = 0; t < T_DIM; ++t) {
    const int p = t & 1;
    v4h nx0 = x0, nx1 = x1;
    const bool pre = (t + 1 < T_DIM);
    bool did_pre = false;
    const size_t nxo = (((size_t)(t+1)*256 + bgrp*64 + ub)*2)*256 + lanep*4;
    // slow path: prefetch before the (long) MALL poll
    if (!fast && pre) {
      nx0 = *(const v4h*)(xp + nxo);
      nx1 = *(const v4h*)(xp + nxo + 256);
      did_pre = true;
    }

    u64* const hb = (p ? gbase1 : gbase0) + tid*2;
    const unsigned target = (unsigned)t;
    unsigned pay0, pay1, pay2, pay3, pay4, pay5, pay6, pay7;
    bool got = false;

    if (fast) {
      const u64* a0 = hb;
      const u64* a1 = hb + 512;
      const u64* a2 = hb + 1024;
      const u64* a3 = hb + 1536;
      int rounds = 0;
      for (;;) {
        v4u q0, q1, q2, q3;
        asm volatile("global_load_dwordx4 %0, %1, off nt"
                     : "=v"(q0) : "v"(a0) : "memory");
        asm volatile("global_load_dwordx4 %0, %1, off nt"
                     : "=v"(q1) : "v"(a1) : "memory");
        asm volatile("global_load_dwordx4 %0, %1, off nt"
                     : "=v"(q2) : "v"(a2) : "memory");
        asm volatile("global_load_dwordx4 %0, %1, off nt"
                     : "=v"(q3) : "v"(a3) : "memory");
        asm volatile("s_waitcnt vmcnt(0)"
                     : "+v"(q0), "+v"(q1), "+v"(q2), "+v"(q3) :: "memory");
        __builtin_amdgcn_sched_barrier(0);
        const unsigned bad = (q0.y ^ target) | (q0.w ^ target)
                           | (q1.y ^ target) | (q1.w ^ target)
                           | (q2.y ^ target) | (q2.w ^ target)
                           | (q3.y ^ target) | (q3.w ^ target);
        if (__all((int)(bad == 0))) {
          pay0 = q0.x; pay1 = q0.z; pay2 = q1.x; pay3 = q1.z;
          pay4 = q2.x; pay5 = q2.z; pay6 = q3.x; pay7 = q3.z;
          got = true;
          break;
        }
        ++rounds;
        if ((rounds & 31) == 16) {
          // watchdog: abort word is agent-scope; on trip, flush the last
          // plain-stored words to MALL and fall back to the slow protocol.
          u64 ab = __hip_atomic_load(abw, __ATOMIC_RELAXED,
                                     __HIP_MEMORY_SCOPE_AGENT);
          if (__any((int)(ab != 0)) || rounds > 512) {
            __hip_atomic_store(abw, (u64)1, __ATOMIC_RELAXED,
                               __HIP_MEMORY_SCOPE_AGENT);
            if (lw0) __hip_atomic_store(gb0p, lw0, __ATOMIC_RELAXED,
                                        __HIP_MEMORY_SCOPE_AGENT);
            if (lw1) __hip_atomic_store(gb1p, lw1, __ATOMIC_RELAXED,
                                        __HIP_MEMORY_SCOPE_AGENT);
            fast = false;
            break;
          }
        }
        __builtin_amdgcn_s_sleep(1);
      }
    }
    if (!got) {
      for (;;) {
        u64 wq[8];
        #pragma unroll
        for (int j = 0; j < 4; ++j) {
          wq[j*2]   = __hip_atomic_load(hb + j*512,     __ATOMIC_RELAXED,
                                        __HIP_MEMORY_SCOPE_AGENT);
          wq[j*2+1] = __hip_atomic_load(hb + j*512 + 1, __ATOMIC_RELAXED,
                                        __HIP_MEMORY_SCOPE_AGENT);
        }
        unsigned bad = 0;
        #pragma unroll
        for (int j = 0; j < 8; ++j)
          bad |= ((unsigned)(wq[j] >> 32)) ^ target;
        if (__all((int)(bad == 0))) {
          pay0 = (unsigned)wq[0]; pay1 = (unsigned)wq[1];
          pay2 = (unsigned)wq[2]; pay3 = (unsigned)wq[3];
          pay4 = (unsigned)wq[4]; pay5 = (unsigned)wq[5];
          pay6 = (unsigned)wq[6]; pay7 = (unsigned)wq[7];
          break;
        }
        __builtin_amdgcn_s_sleep(1);
      }
    }

    // redistribute payload dwords into linear hlds (b64 writes, 2-way free)
    {
      v2u* hl = (v2u*)hlds[p];
      hl[tid]       = (v2u){pay0, pay1};
      hl[tid + 256] = (v2u){pay2, pay3};
      hl[tid + 512] = (v2u){pay4, pay5};
      hl[tid + 768] = (v2u){pay6, pay7};
    }
    __syncthreads();

    // fast path (or post-abort catch-up): prefetch after the barrier so the
    // poll's vmcnt(0) doesn't serialize the ~900cy HBM latency into the wait
    if (pre && !did_pre) {
      nx0 = *(const v4h*)(xp + nxo);
      nx1 = *(const v4h*)(xp + nxo + 256);
    }

    v4f acc0 = { (float)x0[0], (float)x0[1], (float)x0[2], (float)x0[3] };
    v4f acc1 = { (float)x1[0], (float)x1[1], (float)x1[2], (float)x1[3] };
    v4f acc2 = { 0.f, 0.f, 0.f, 0.f };
    v4f acc3 = { 0.f, 0.f, 0.f, 0.f };
    const unsigned* hfr = &hlds[p][hbase];
    #pragma unroll
    for (int kk = 0; kk < 8; ++kk) {
      v8h a0 = *(const v8h*)(hfr + kk*hoff);
      v8h a1 = *(const v8h*)(hfr + (kk+8)*hoff);
      acc0 = __builtin_amdgcn_mfma_f32_16x16x32_f16(a0, bF0[kk],   acc0, 0,0,0);
      acc1 = __builtin_amdgcn_mfma_f32_16x16x32_f16(a0, bF1[kk],   acc1, 0,0,0);
      acc2 = __builtin_amdgcn_mfma_f32_16x16x32_f16(a1, bF0[kk+8], acc2, 0,0,0);
      acc3 = __builtin_amdgcn_mfma_f32_16x16x32_f16(a1, bF1[kk+8], acc3, 0,0,0);
    }
    acc0 += acc2; acc1 += acc3;

    // gate exchange within wave (rows 0..7 valid; pad rows written, unused)
    float* gb = gbuf[wv];
    #pragma unroll
    for (int r = 0; r < 4; ++r) {
      const int row = quad*4 + r;
      gb[row*33 + n]      = acc0[r];
      gb[row*33 + 16 + n] = acc1[r];
    }
    __builtin_amdgcn_wave_barrier();
    const float* gr = gb + n*33;
    const int ua2 = quad*2;
    float gi0 = gr[ua2],   gf0 = gr[8+ua2], gg0 = gr[16+ua2], go0 = gr[24+ua2];
    float gi1 = gr[ua2+1], gf1 = gr[9+ua2], gg1 = gr[17+ua2], go1 = gr[25+ua2];
    __builtin_amdgcn_wave_barrier();

    gi0 = fsig(gi0); gf0 = fsig(gf0); gg0 = ftanh(gg0); go0 = fsig(go0);
    gi1 = fsig(gi1); gf1 = fsig(gf1); gg1 = ftanh(gg1); go1 = fsig(go1);
    c0 = gf0*c0 + gi0*gg0;  hf0 = go0*ftanh(c0);
    c1 = gf1*c1 + gi1*gg1;  hf1 = go1*ftanh(c1);

    // tagged h store: fast = plain (write-back into the shared XCD L2);
    // slow = agent-scope (write-through to MALL)
    if (t < T_DIM - 1 && act) {
      union { v2h v; unsigned u; } pw;
      pw.v = (v2h){ (h16)hf0, (h16)hf1 };
      const u64 word = ((u64)(unsigned)(t + 1) << 32) | (u64)pw.u;
      u64* const hwp = (p ? gbase0 : gbase1) + pW;
      if (fast) {
        __hip_atomic_store(hwp, word, __ATOMIC_RELAXED,
                           __HIP_MEMORY_SCOPE_WORKGROUP);
        if (p) lw0 = word; else lw1 = word;
      } else {
        __hip_atomic_store(hwp, word, __ATOMIC_RELAXED,
                           __HIP_MEMORY_SCOPE_AGENT);
      }
    }
    x0 = nx0; x1 = nx1;
  }

  if (act) {
    float* oc = out + (size_t)(g*GROWS + n)*H_DIM + u0 + quad*2;
    oc[0] = c0; oc[1] = c1;
    oc[HSZ + 0] = hf0; oc[HSZ + 1] = hf1;
  }
}

extern "C" void kernel_launch(void* const* d_in, const int* in_sizes, int n_in,
                              void* d_out, int out_size, void* d_ws, size_t ws_size,
                              hipStream_t stream) {
  const float* X    = (const float*)d_in[0];
  const float* Wx   = (const float*)d_in[1];
  const float* Wh   = (const float*)d_in[2];
  const float* bias = (const float*)d_in[3];
  float* out = (float*)d_out;

  char* ws = (char*)d_ws;
  h16* xp   = (h16*)ws;
  u64* hbuf = (u64*)(ws + XP_BYTES);
  h16* X16  = (h16*)(ws + XP_BYTES + HB_BYTES);
  h16* Wxp  = (h16*)(ws + XP_BYTES + HB_BYTES + X16_BYTES);

  // zero hbuf + census/trial/vote/abort words (tags -> 0 == t=0 target)
  hipMemsetAsync(ws + XP_BYTES, 0, HB_BYTES, stream);

  conv_x_kernel<<<4096, 256, 0, stream>>>(X, X16);
  conv_w_kernel<<<512, 256, 0, stream>>>(Wx, Wxp);
  xproj_kernel<<<8192, 256, 0, stream>>>(X16, Wxp, bias, xp);
  scan_kernel<<<NWG, 256, 0, stream>>>(Wh, xp, hbuf, out);
}